// Round 11
// baseline (226.862 us; speedup 1.0000x reference)
//
#include <hip/hip_runtime.h>

#define SEQ   2048
#define DIM   64
#define NB    2
#define NH    16
#define NHEAD (NB * NH)
#define BQ    128
#define BK    64
#define NKT   (SEQ / BK)
#define NQT   (SEQ / BQ)
#define QSCALE 0.18033688011112042f  /* log2(e)/sqrt(64) */

typedef float  f32x4  __attribute__((ext_vector_type(4)));
typedef short  bf16x8 __attribute__((ext_vector_type(8)));
typedef short  s16x4  __attribute__((ext_vector_type(4)));
typedef unsigned short u16;
typedef u16    u16x8  __attribute__((ext_vector_type(8)));
typedef unsigned int u32x4 __attribute__((ext_vector_type(4)));

__device__ __forceinline__ short f2bf(float x) {
    unsigned u = __float_as_uint(x);
    return (short)((u + 0x7FFFu + ((u >> 16) & 1u)) >> 16);
}

__device__ __forceinline__ unsigned cvtpk(float lo, float hi) {
    unsigned r;
    asm("v_cvt_pk_bf16_f32 %0, %1, %2" : "=v"(r) : "v"(lo), "v"(hi));
    return r;
}

// async global->LDS, 16B per lane
__device__ __forceinline__ void gll16(const void* g, void* l) {
    __builtin_amdgcn_global_load_lds(
        (const __attribute__((address_space(1))) unsigned int*)g,
        (__attribute__((address_space(3))) unsigned int*)l, 16, 0, 0);
}

// fragment from linear [64][64] bf16 tile stored with per-row XOR swizzle:
// stored_byte[b] = plain_byte[b ^ ((row&7)<<4)]. slots {kbase..+3, kbase+16..+19}
__device__ __forceinline__ bf16x8 ldfrag_swz(const u16* tile, int row, int kbase) {
    const char* rp = (const char*)(tile + row * 64);
    const int sw = (row & 7) << 4;
    s16x4 lo = *reinterpret_cast<const s16x4*>(rp + (((kbase << 1)     ) ^ sw));
    s16x4 hi = *reinterpret_cast<const s16x4*>(rp + (((kbase << 1) + 32) ^ sw));
    bf16x8 f;
    f[0] = lo[0]; f[1] = lo[1]; f[2] = lo[2]; f[3] = lo[3];
    f[4] = hi[0]; f[5] = hi[1]; f[6] = hi[2]; f[7] = hi[3];
    return f;
}

// ---------- pre-kernel: K f32 -> bf16, tiled + XOR-swizzled ----------
__global__ __launch_bounds__(256)
void conv_k_kernel(const float* __restrict__ K, u16* __restrict__ Kp)
{
    const int idx = (int)blockIdx.x * 256 + (int)threadIdx.x;
    const int u  = idx & 7;
    const int r  = (idx >> 3) & 63;
    const int kt = (idx >> 9) & 31;
    const int h  = idx >> 14;
    const int d0 = ((u ^ (r & 7)) << 3);
    const float* src = K + (((size_t)h * SEQ + (size_t)kt * 64 + r) * DIM + d0);
    const float4 a = *reinterpret_cast<const float4*>(src);
    const float4 b = *reinterpret_cast<const float4*>(src + 4);
    u16x8 o;
    o[0] = (u16)f2bf(a.x); o[1] = (u16)f2bf(a.y); o[2] = (u16)f2bf(a.z); o[3] = (u16)f2bf(a.w);
    o[4] = (u16)f2bf(b.x); o[5] = (u16)f2bf(b.y); o[6] = (u16)f2bf(b.z); o[7] = (u16)f2bf(b.w);
    *reinterpret_cast<u16x8*>(Kp + (size_t)idx * 8) = o;
}

// ---------- pre-kernel: V f32 -> bf16 transposed (V^T[d][key]) + swizzled ----------
__global__ __launch_bounds__(256)
void conv_v_kernel(const float* __restrict__ V, u16* __restrict__ Vp)
{
    __shared__ float tile[64][65];
    const int tid = (int)threadIdx.x;
    const int h   = (int)blockIdx.x >> 5;
    const int kt  = (int)blockIdx.x & 31;

    const int row0 = tid >> 4;
    const int c0   = (tid & 15) << 2;
    #pragma unroll
    for (int i = 0; i < 4; ++i) {
        const int row = row0 + (i << 4);
        const float4 v = *reinterpret_cast<const float4*>(
            V + (((size_t)h * SEQ + (size_t)kt * 64 + row) * DIM + c0));
        tile[row][c0 + 0] = v.x; tile[row][c0 + 1] = v.y;
        tile[row][c0 + 2] = v.z; tile[row][c0 + 3] = v.w;
    }
    __syncthreads();

    #pragma unroll
    for (int i = 0; i < 2; ++i) {
        const int oi = tid + i * 256;
        const int u  = oi & 7;
        const int rd = oi >> 3;
        const int k0 = ((u ^ (rd & 7)) << 3);
        u16x8 o;
        #pragma unroll
        for (int j = 0; j < 8; ++j)
            o[j] = (u16)f2bf(tile[k0 + j][rd]);
        *reinterpret_cast<u16x8*>(Vp + ((size_t)((h * 32 + kt) * 512 + oi)) * 8) = o;
    }
}

// ---------- main fused kernel: 512 threads, BQ=128, 3-buffer pipeline ----------
__global__ __launch_bounds__(512, 4)
void sdpa_main_kernel(const float* __restrict__ Qp, const u16* __restrict__ Kp,
                      const u16* __restrict__ Vp, const int* __restrict__ Mp,
                      float* __restrict__ Op, float* __restrict__ Pg_)
{
    __shared__ u16   Ks[3][4096];
    __shared__ u16   Vs[3][4096];
    __shared__ float Fb[SEQ];

    const int tid  = (int)threadIdx.x;
    const int lane = tid & 63;
    const int w    = tid >> 6;            // wave 0..7, owns q-rows w*16..w*16+15
    const int mrow = lane & 15;
    const int kgrp = (lane >> 4) << 2;

    // XCD-clustered decomposition: 512 blocks, xcd = bid & 7.
    const int bid  = (int)blockIdx.x;
    const int xcd  = bid & 7;
    const int slot = bid >> 3;            // 0..63
    const int bh   = xcd * 4 + (slot >> 4);
    const int qt   = slot & 15;

    const size_t headoff = (size_t)bh * SEQ * DIM;
    const float* Qg = Qp + headoff + (size_t)qt * BQ * DIM;
    const u16*   Kh = Kp + (size_t)bh * NKT * 4096;
    const u16*   Vh = Vp + (size_t)bh * NKT * 4096;
    const int*   Mg = Mp + (size_t)(bh / NH) * SEQ;
    float*       Og = Op + headoff + (size_t)qt * BQ * DIM;
    float*       Pg = Pg_ + ((size_t)bh * SEQ + (size_t)qt * BQ) * SEQ;

    // ---- mask -> additive log2-domain bias in LDS (once) ----
    {
        const int4 m0 = *reinterpret_cast<const int4*>(Mg + tid * 4);
        float4 f0;
        f0.x = m0.x ? -1.0e9f : 0.0f; f0.y = m0.y ? -1.0e9f : 0.0f;
        f0.z = m0.z ? -1.0e9f : 0.0f; f0.w = m0.w ? -1.0e9f : 0.0f;
        *reinterpret_cast<float4*>(&Fb[tid * 4]) = f0;
    }

    // ---- Q fragments: global -> regs directly (scale folded) ----
    bf16x8 qf0, qf1;
    {
        const float* qrow = Qg + (size_t)(w * 16 + mrow) * DIM;
        const float4 a = *reinterpret_cast<const float4*>(qrow + kgrp);
        const float4 b = *reinterpret_cast<const float4*>(qrow + 16 + kgrp);
        const float4 c = *reinterpret_cast<const float4*>(qrow + 32 + kgrp);
        const float4 d = *reinterpret_cast<const float4*>(qrow + 48 + kgrp);
        qf0[0] = f2bf(a.x * QSCALE); qf0[1] = f2bf(a.y * QSCALE);
        qf0[2] = f2bf(a.z * QSCALE); qf0[3] = f2bf(a.w * QSCALE);
        qf0[4] = f2bf(b.x * QSCALE); qf0[5] = f2bf(b.y * QSCALE);
        qf0[6] = f2bf(b.z * QSCALE); qf0[7] = f2bf(b.w * QSCALE);
        qf1[0] = f2bf(c.x * QSCALE); qf1[1] = f2bf(c.y * QSCALE);
        qf1[2] = f2bf(c.z * QSCALE); qf1[3] = f2bf(c.w * QSCALE);
        qf1[4] = f2bf(d.x * QSCALE); qf1[5] = f2bf(d.y * QSCALE);
        qf1[6] = f2bf(d.z * QSCALE); qf1[7] = f2bf(d.w * QSCALE);
    }
    __syncthreads();   // Fb visible to all waves

    const int so = tid * 8;   // staging offset (u16 units): 512 thr * 16B = one tile

    // ===== pass 1: lsum for this lane's q-row (depth-2 prefetch, K only) =====
    gll16(Kh + so, &Ks[0][so]);
    gll16(Kh + 4096 + so, &Ks[1][so]);
    asm volatile("s_waitcnt vmcnt(1)" ::: "memory");
    __builtin_amdgcn_s_barrier();

    float lsum = 0.f;
    int bcur = 0, bpre = 2;

    for (int kt = 0; kt < NKT; ++kt) {
        gll16(Kh + (size_t)((kt + 2) & (NKT - 1)) * 4096 + so, &Ks[bpre][so]);
        // queue: [G(kt+1)][G(kt+2)] after G(kt) retires -> vmcnt(2)
        asm volatile("s_waitcnt vmcnt(2)" ::: "memory");
        __builtin_amdgcn_s_barrier();
        __builtin_amdgcn_sched_barrier(0);

        const int k0 = kt * BK;
        #pragma unroll
        for (int t = 0; t < 4; ++t) {
            const bf16x8 kf0 = ldfrag_swz(Ks[bcur], t * 16 + mrow, kgrp);
            const bf16x8 kf1 = ldfrag_swz(Ks[bcur], t * 16 + mrow, 32 + kgrp);
            f32x4 a = {0.f, 0.f, 0.f, 0.f};
            a = __builtin_amdgcn_mfma_f32_16x16x32_bf16(kf0, qf0, a, 0, 0, 0);
            a = __builtin_amdgcn_mfma_f32_16x16x32_bf16(kf1, qf1, a, 0, 0, 0);
            const float4 b = *reinterpret_cast<const float4*>(&Fb[k0 + t * 16 + kgrp]);
            lsum += __builtin_amdgcn_exp2f(a[0] + b.x);
            lsum += __builtin_amdgcn_exp2f(a[1] + b.y);
            lsum += __builtin_amdgcn_exp2f(a[2] + b.z);
            lsum += __builtin_amdgcn_exp2f(a[3] + b.w);
        }

        asm volatile("s_waitcnt lgkmcnt(0)" ::: "memory");
        __builtin_amdgcn_s_barrier();   // reads of Ks[bcur] done before overwrite
        bcur = (bcur == 2) ? 0 : bcur + 1;
        bpre = (bpre == 2) ? 0 : bpre + 1;
    }

    // drain leftover wraparound prefetches before pass 2 re-stages same buffers
    asm volatile("s_waitcnt vmcnt(0)" ::: "memory");

    lsum += __shfl_xor(lsum, 16);
    lsum += __shfl_xor(lsum, 32);
    const float rinv = 1.0f / lsum;

    __builtin_amdgcn_s_barrier();   // all waves drained before pass-2 staging

    // ===== pass 2: P (normalized, in-register) -> NT store + PV accumulate =====
    f32x4 oacc[4];
    #pragma unroll
    for (int n = 0; n < 4; ++n) {
        oacc[n][0] = 0.f; oacc[n][1] = 0.f; oacc[n][2] = 0.f; oacc[n][3] = 0.f;
    }

    gll16(Kh + so, &Ks[0][so]);
    gll16(Vh + so, &Vs[0][so]);
    gll16(Kh + 4096 + so, &Ks[1][so]);
    gll16(Vh + 4096 + so, &Vs[1][so]);
    asm volatile("s_waitcnt vmcnt(2)" ::: "memory");   // K0,V0 retired
    __builtin_amdgcn_s_barrier();
    bcur = 0; bpre = 2;

    float* prow = Pg + (size_t)(w * 16 + mrow) * SEQ + kgrp;

    for (int kt = 0; kt < NKT; ++kt) {
        {   // prefetch tiles kt+2
            const size_t nt = (size_t)((kt + 2) & (NKT - 1)) * 4096;
            gll16(Kh + nt + so, &Ks[bpre][so]);
            gll16(Vh + nt + so, &Vs[bpre][so]);
        }
        // steady queue: [KV(kt) 2][S(kt-2) 4][KV(kt+1) 2][S(kt-1) 4][KV(kt+2) 2]=14
        // vmcnt(8) retires KV(kt) + S(kt-2): stores get 2+ iterations of slack
        asm volatile("s_waitcnt vmcnt(8)" ::: "memory");
        __builtin_amdgcn_s_barrier();
        __builtin_amdgcn_sched_barrier(0);

        const int k0 = kt * BK;
        bf16x8 pf0, pf1;

        #pragma unroll
        for (int half = 0; half < 2; ++half) {
            f32x4 p[2];
            #pragma unroll
            for (int i = 0; i < 2; ++i) {
                const int t = half * 2 + i;
                const bf16x8 kf0 = ldfrag_swz(Ks[bcur], t * 16 + mrow, kgrp);
                const bf16x8 kf1 = ldfrag_swz(Ks[bcur], t * 16 + mrow, 32 + kgrp);
                f32x4 a = {0.f, 0.f, 0.f, 0.f};
                a = __builtin_amdgcn_mfma_f32_16x16x32_bf16(kf0, qf0, a, 0, 0, 0);
                a = __builtin_amdgcn_mfma_f32_16x16x32_bf16(kf1, qf1, a, 0, 0, 0);
                const float4 b = *reinterpret_cast<const float4*>(&Fb[k0 + t * 16 + kgrp]);
                p[i][0] = __builtin_amdgcn_exp2f(a[0] + b.x) * rinv;
                p[i][1] = __builtin_amdgcn_exp2f(a[1] + b.y) * rinv;
                p[i][2] = __builtin_amdgcn_exp2f(a[2] + b.z) * rinv;
                p[i][3] = __builtin_amdgcn_exp2f(a[3] + b.w) * rinv;
                __builtin_nontemporal_store(
                    p[i], reinterpret_cast<f32x4*>(prow + k0 + t * 16));
            }
            const u32x4 packed = { cvtpk(p[0][0], p[0][1]), cvtpk(p[0][2], p[0][3]),
                                   cvtpk(p[1][0], p[1][1]), cvtpk(p[1][2], p[1][3]) };
            if (half == 0) pf0 = __builtin_bit_cast(bf16x8, packed);
            else           pf1 = __builtin_bit_cast(bf16x8, packed);
        }

        #pragma unroll
        for (int n = 0; n < 4; ++n) {
            const bf16x8 vf0 = ldfrag_swz(Vs[bcur], n * 16 + mrow, kgrp);
            const bf16x8 vf1 = ldfrag_swz(Vs[bcur], n * 16 + mrow, 32 + kgrp);
            oacc[n] = __builtin_amdgcn_mfma_f32_16x16x32_bf16(pf0, vf0, oacc[n], 0, 0, 0);
            oacc[n] = __builtin_amdgcn_mfma_f32_16x16x32_bf16(pf1, vf1, oacc[n], 0, 0, 0);
        }

        asm volatile("s_waitcnt lgkmcnt(0)" ::: "memory");
        __builtin_amdgcn_s_barrier();   // reads of buf[bcur] done before overwrite
        bcur = (bcur == 2) ? 0 : bcur + 1;
        bpre = (bpre == 2) ? 0 : bpre + 1;
    }

    #pragma unroll
    for (int n = 0; n < 4; ++n) {
        #pragma unroll
        for (int r = 0; r < 4; ++r)
            __builtin_nontemporal_store(
                oacc[n][r], &Og[(size_t)(w * 16 + kgrp + r) * DIM + n * 16 + mrow]);
    }
}

extern "C" void kernel_launch(void* const* d_in, const int* in_sizes, int n_in,
                              void* d_out, int out_size, void* d_ws, size_t ws_size,
                              hipStream_t stream) {
    const float* Q = (const float*)d_in[0];
    const float* K = (const float*)d_in[1];
    const float* V = (const float*)d_in[2];
    const int*   M = (const int*)d_in[3];
    float* O = (float*)d_out;
    float* P = O + (size_t)NB * NH * SEQ * DIM;

    u16* Kp = (u16*)d_ws;                                   // 8 MB
    u16* Vp = Kp + (size_t)NHEAD * SEQ * DIM;               // 8 MB (total exactly 16 MB)

    conv_k_kernel<<<dim3(NHEAD * NKT * 64 * 8 / 256), dim3(256), 0, stream>>>(K, Kp);
    conv_v_kernel<<<dim3(NHEAD * NKT), dim3(256), 0, stream>>>(V, Vp);

    sdpa_main_kernel<<<dim3(NHEAD * NQT), dim3(512, 1, 1), 0, stream>>>(Q, Kp, Vp, M, O, P);
}

// Round 12
// 189.533 us; speedup vs baseline: 1.1969x; 1.1969x over previous
//
#include <hip/hip_runtime.h>

#define SEQ   2048
#define DIM   64
#define NB    2
#define NH    16
#define NHEAD (NB * NH)
#define BQ    128
#define BK    64
#define NKT   (SEQ / BK)
#define NQT   (SEQ / BQ)
#define QSCALE 0.18033688011112042f  /* log2(e)/sqrt(64) */

typedef float  f32x4  __attribute__((ext_vector_type(4)));
typedef short  bf16x8 __attribute__((ext_vector_type(8)));
typedef short  s16x4  __attribute__((ext_vector_type(4)));
typedef unsigned short u16;
typedef u16    u16x8  __attribute__((ext_vector_type(8)));
typedef unsigned int u32x4 __attribute__((ext_vector_type(4)));

__device__ __forceinline__ short f2bf(float x) {
    unsigned u = __float_as_uint(x);
    return (short)((u + 0x7FFFu + ((u >> 16) & 1u)) >> 16);
}

__device__ __forceinline__ unsigned cvtpk(float lo, float hi) {
    unsigned r;
    asm("v_cvt_pk_bf16_f32 %0, %1, %2" : "=v"(r) : "v"(lo), "v"(hi));
    return r;
}

// async global->LDS, 16B per lane
__device__ __forceinline__ void gll16(const void* g, void* l) {
    __builtin_amdgcn_global_load_lds(
        (const __attribute__((address_space(1))) unsigned int*)g,
        (__attribute__((address_space(3))) unsigned int*)l, 16, 0, 0);
}

// fragment from linear [64][64] bf16 tile stored with per-row XOR swizzle:
// stored_byte[b] = plain_byte[b ^ ((row&7)<<4)]. slots {kbase..+3, kbase+16..+19}
__device__ __forceinline__ bf16x8 ldfrag_swz(const u16* tile, int row, int kbase) {
    const char* rp = (const char*)(tile + row * 64);
    const int sw = (row & 7) << 4;
    s16x4 lo = *reinterpret_cast<const s16x4*>(rp + (((kbase << 1)     ) ^ sw));
    s16x4 hi = *reinterpret_cast<const s16x4*>(rp + (((kbase << 1) + 32) ^ sw));
    bf16x8 f;
    f[0] = lo[0]; f[1] = lo[1]; f[2] = lo[2]; f[3] = lo[3];
    f[4] = hi[0]; f[5] = hi[1]; f[6] = hi[2]; f[7] = hi[3];
    return f;
}

// ---------- pre-kernel: K f32 -> bf16, tiled + XOR-swizzled ----------
__global__ __launch_bounds__(256)
void conv_k_kernel(const float* __restrict__ K, u16* __restrict__ Kp)
{
    const int idx = (int)blockIdx.x * 256 + (int)threadIdx.x;
    const int u  = idx & 7;
    const int r  = (idx >> 3) & 63;
    const int kt = (idx >> 9) & 31;
    const int h  = idx >> 14;
    const int d0 = ((u ^ (r & 7)) << 3);
    const float* src = K + (((size_t)h * SEQ + (size_t)kt * 64 + r) * DIM + d0);
    const float4 a = *reinterpret_cast<const float4*>(src);
    const float4 b = *reinterpret_cast<const float4*>(src + 4);
    u16x8 o;
    o[0] = (u16)f2bf(a.x); o[1] = (u16)f2bf(a.y); o[2] = (u16)f2bf(a.z); o[3] = (u16)f2bf(a.w);
    o[4] = (u16)f2bf(b.x); o[5] = (u16)f2bf(b.y); o[6] = (u16)f2bf(b.z); o[7] = (u16)f2bf(b.w);
    *reinterpret_cast<u16x8*>(Kp + (size_t)idx * 8) = o;
}

// ---------- pre-kernel: V f32 -> bf16 transposed (V^T[d][key]) + swizzled ----------
__global__ __launch_bounds__(256)
void conv_v_kernel(const float* __restrict__ V, u16* __restrict__ Vp)
{
    __shared__ float tile[64][65];
    const int tid = (int)threadIdx.x;
    const int h   = (int)blockIdx.x >> 5;
    const int kt  = (int)blockIdx.x & 31;

    const int row0 = tid >> 4;
    const int c0   = (tid & 15) << 2;
    #pragma unroll
    for (int i = 0; i < 4; ++i) {
        const int row = row0 + (i << 4);
        const float4 v = *reinterpret_cast<const float4*>(
            V + (((size_t)h * SEQ + (size_t)kt * 64 + row) * DIM + c0));
        tile[row][c0 + 0] = v.x; tile[row][c0 + 1] = v.y;
        tile[row][c0 + 2] = v.z; tile[row][c0 + 3] = v.w;
    }
    __syncthreads();

    #pragma unroll
    for (int i = 0; i < 2; ++i) {
        const int oi = tid + i * 256;
        const int u  = oi & 7;
        const int rd = oi >> 3;
        const int k0 = ((u ^ (rd & 7)) << 3);
        u16x8 o;
        #pragma unroll
        for (int j = 0; j < 8; ++j)
            o[j] = (u16)f2bf(tile[k0 + j][rd]);
        *reinterpret_cast<u16x8*>(Vp + ((size_t)((h * 32 + kt) * 512 + oi)) * 8) = o;
    }
}

// ---------- main fused kernel: 512 threads, BQ=128, 3-buffer, 1 barrier/iter ----------
__global__ __launch_bounds__(512, 4)
void sdpa_main_kernel(const float* __restrict__ Qp, const u16* __restrict__ Kp,
                      const u16* __restrict__ Vp, const int* __restrict__ Mp,
                      float* __restrict__ Op, float* __restrict__ Pg_)
{
    __shared__ u16   Ks[3][4096];
    __shared__ u16   Vs[3][4096];
    __shared__ float Fb[SEQ];

    const int tid  = (int)threadIdx.x;
    const int lane = tid & 63;
    const int w    = tid >> 6;            // wave 0..7, owns q-rows w*16..w*16+15
    const int mrow = lane & 15;
    const int kgrp = (lane >> 4) << 2;

    // XCD-clustered decomposition: 512 blocks, xcd = bid & 7.
    const int bid  = (int)blockIdx.x;
    const int xcd  = bid & 7;
    const int slot = bid >> 3;            // 0..63
    const int bh   = xcd * 4 + (slot >> 4);
    const int qt   = slot & 15;

    const size_t headoff = (size_t)bh * SEQ * DIM;
    const float* Qg = Qp + headoff + (size_t)qt * BQ * DIM;
    const u16*   Kh = Kp + (size_t)bh * NKT * 4096;
    const u16*   Vh = Vp + (size_t)bh * NKT * 4096;
    const int*   Mg = Mp + (size_t)(bh / NH) * SEQ;
    float*       Og = Op + headoff + (size_t)qt * BQ * DIM;
    float*       Pg = Pg_ + ((size_t)bh * SEQ + (size_t)qt * BQ) * SEQ;

    // ---- mask -> additive log2-domain bias in LDS (once) ----
    {
        const int4 m0 = *reinterpret_cast<const int4*>(Mg + tid * 4);
        float4 f0;
        f0.x = m0.x ? -1.0e9f : 0.0f; f0.y = m0.y ? -1.0e9f : 0.0f;
        f0.z = m0.z ? -1.0e9f : 0.0f; f0.w = m0.w ? -1.0e9f : 0.0f;
        *reinterpret_cast<float4*>(&Fb[tid * 4]) = f0;
    }

    // ---- Q fragments: global -> regs directly (scale folded) ----
    bf16x8 qf0, qf1;
    {
        const float* qrow = Qg + (size_t)(w * 16 + mrow) * DIM;
        const float4 a = *reinterpret_cast<const float4*>(qrow + kgrp);
        const float4 b = *reinterpret_cast<const float4*>(qrow + 16 + kgrp);
        const float4 c = *reinterpret_cast<const float4*>(qrow + 32 + kgrp);
        const float4 d = *reinterpret_cast<const float4*>(qrow + 48 + kgrp);
        qf0[0] = f2bf(a.x * QSCALE); qf0[1] = f2bf(a.y * QSCALE);
        qf0[2] = f2bf(a.z * QSCALE); qf0[3] = f2bf(a.w * QSCALE);
        qf0[4] = f2bf(b.x * QSCALE); qf0[5] = f2bf(b.y * QSCALE);
        qf0[6] = f2bf(b.z * QSCALE); qf0[7] = f2bf(b.w * QSCALE);
        qf1[0] = f2bf(c.x * QSCALE); qf1[1] = f2bf(c.y * QSCALE);
        qf1[2] = f2bf(c.z * QSCALE); qf1[3] = f2bf(c.w * QSCALE);
        qf1[4] = f2bf(d.x * QSCALE); qf1[5] = f2bf(d.y * QSCALE);
        qf1[6] = f2bf(d.z * QSCALE); qf1[7] = f2bf(d.w * QSCALE);
    }
    __syncthreads();   // Fb visible to all waves

    const int so = tid * 8;   // staging offset (u16 units): 512 thr * 16B = one tile

    // ===== pass 1: lsum (depth-2 prefetch, K only, 1 barrier/iter) =====
    gll16(Kh + so, &Ks[0][so]);
    gll16(Kh + 4096 + so, &Ks[1][so]);

    float lsum = 0.f;
    int bcur = 0, bpre = 2;

    for (int kt = 0; kt < NKT; ++kt) {
        // outstanding at top: G(kt), G(kt+1) -> vmcnt(1) retires G(kt)
        asm volatile("s_waitcnt vmcnt(1)" ::: "memory");
        __builtin_amdgcn_s_barrier();
        // prefetch into buf (bcur+2)%3 = buffer read at iter kt-1; barrier above
        // guarantees those reads completed (consumed by MFMAs before the barrier).
        gll16(Kh + (size_t)((kt + 2) & (NKT - 1)) * 4096 + so, &Ks[bpre][so]);
        __builtin_amdgcn_sched_barrier(0);

        const int k0 = kt * BK;
        #pragma unroll
        for (int t = 0; t < 4; ++t) {
            const bf16x8 kf0 = ldfrag_swz(Ks[bcur], t * 16 + mrow, kgrp);
            const bf16x8 kf1 = ldfrag_swz(Ks[bcur], t * 16 + mrow, 32 + kgrp);
            f32x4 a = {0.f, 0.f, 0.f, 0.f};
            a = __builtin_amdgcn_mfma_f32_16x16x32_bf16(kf0, qf0, a, 0, 0, 0);
            a = __builtin_amdgcn_mfma_f32_16x16x32_bf16(kf1, qf1, a, 0, 0, 0);
            const float4 b = *reinterpret_cast<const float4*>(&Fb[k0 + t * 16 + kgrp]);
            lsum += __builtin_amdgcn_exp2f(a[0] + b.x);
            lsum += __builtin_amdgcn_exp2f(a[1] + b.y);
            lsum += __builtin_amdgcn_exp2f(a[2] + b.z);
            lsum += __builtin_amdgcn_exp2f(a[3] + b.w);
        }

        bcur = (bcur == 2) ? 0 : bcur + 1;
        bpre = (bpre == 2) ? 0 : bpre + 1;
    }

    // drain leftover wraparound prefetches before pass 2 re-stages same buffers
    asm volatile("s_waitcnt vmcnt(0)" ::: "memory");

    lsum += __shfl_xor(lsum, 16);
    lsum += __shfl_xor(lsum, 32);
    const float rinv = 1.0f / lsum;

    __builtin_amdgcn_s_barrier();   // all waves drained before pass-2 staging

    // ===== pass 2: P -> global (normal stores) + PV accumulate =====
    f32x4 oacc[4];
    #pragma unroll
    for (int n = 0; n < 4; ++n) {
        oacc[n][0] = 0.f; oacc[n][1] = 0.f; oacc[n][2] = 0.f; oacc[n][3] = 0.f;
    }

    gll16(Kh + so, &Ks[0][so]);
    gll16(Vh + so, &Vs[0][so]);
    gll16(Kh + 4096 + so, &Ks[1][so]);
    gll16(Vh + 4096 + so, &Vs[1][so]);
    asm volatile("s_waitcnt vmcnt(2)" ::: "memory");   // peel: KV(0) retired
    __builtin_amdgcn_s_barrier();
    bcur = 0; bpre = 2;

    float* prow = Pg + (size_t)(w * 16 + mrow) * SEQ + kgrp;

    for (int kt = 0; kt < NKT; ++kt) {
        // steady state: younger-than-KV(kt) = S(kt-2)4 + KV(kt+1)2 + S(kt-1)4 = 10
        // kt==1: younger-than-KV(1) = KV(2)2 + S(0)4 = 6.  kt==0 covered by peel.
        if (kt == 1) { asm volatile("s_waitcnt vmcnt(6)" ::: "memory"); }
        else         { asm volatile("s_waitcnt vmcnt(10)" ::: "memory"); }
        __builtin_amdgcn_s_barrier();
        {   // prefetch tiles kt+2 into buffer read at iter kt-1 (safe per barrier)
            const size_t nt = (size_t)((kt + 2) & (NKT - 1)) * 4096;
            gll16(Kh + nt + so, &Ks[bpre][so]);
            gll16(Vh + nt + so, &Vs[bpre][so]);
        }
        __builtin_amdgcn_sched_barrier(0);

        const int k0 = kt * BK;
        bf16x8 pf0, pf1;

        #pragma unroll
        for (int half = 0; half < 2; ++half) {
            f32x4 p[2];
            #pragma unroll
            for (int i = 0; i < 2; ++i) {
                const int t = half * 2 + i;
                const bf16x8 kf0 = ldfrag_swz(Ks[bcur], t * 16 + mrow, kgrp);
                const bf16x8 kf1 = ldfrag_swz(Ks[bcur], t * 16 + mrow, 32 + kgrp);
                f32x4 a = {0.f, 0.f, 0.f, 0.f};
                a = __builtin_amdgcn_mfma_f32_16x16x32_bf16(kf0, qf0, a, 0, 0, 0);
                a = __builtin_amdgcn_mfma_f32_16x16x32_bf16(kf1, qf1, a, 0, 0, 0);
                const float4 b = *reinterpret_cast<const float4*>(&Fb[k0 + t * 16 + kgrp]);
                p[i][0] = __builtin_amdgcn_exp2f(a[0] + b.x) * rinv;
                p[i][1] = __builtin_amdgcn_exp2f(a[1] + b.y) * rinv;
                p[i][2] = __builtin_amdgcn_exp2f(a[2] + b.z) * rinv;
                p[i][3] = __builtin_amdgcn_exp2f(a[3] + b.w) * rinv;
                *reinterpret_cast<float4*>(prow + k0 + t * 16) =
                    *reinterpret_cast<const float4*>(&p[i]);
            }
            const u32x4 packed = { cvtpk(p[0][0], p[0][1]), cvtpk(p[0][2], p[0][3]),
                                   cvtpk(p[1][0], p[1][1]), cvtpk(p[1][2], p[1][3]) };
            if (half == 0) pf0 = __builtin_bit_cast(bf16x8, packed);
            else           pf1 = __builtin_bit_cast(bf16x8, packed);
        }

        #pragma unroll
        for (int n = 0; n < 4; ++n) {
            const bf16x8 vf0 = ldfrag_swz(Vs[bcur], n * 16 + mrow, kgrp);
            const bf16x8 vf1 = ldfrag_swz(Vs[bcur], n * 16 + mrow, 32 + kgrp);
            oacc[n] = __builtin_amdgcn_mfma_f32_16x16x32_bf16(pf0, vf0, oacc[n], 0, 0, 0);
            oacc[n] = __builtin_amdgcn_mfma_f32_16x16x32_bf16(pf1, vf1, oacc[n], 0, 0, 0);
        }

        bcur = (bcur == 2) ? 0 : bcur + 1;
        bpre = (bpre == 2) ? 0 : bpre + 1;
    }

    #pragma unroll
    for (int n = 0; n < 4; ++n) {
        #pragma unroll
        for (int r = 0; r < 4; ++r)
            Og[(size_t)(w * 16 + kgrp + r) * DIM + n * 16 + mrow] = oacc[n][r];
    }
}

extern "C" void kernel_launch(void* const* d_in, const int* in_sizes, int n_in,
                              void* d_out, int out_size, void* d_ws, size_t ws_size,
                              hipStream_t stream) {
    const float* Q = (const float*)d_in[0];
    const float* K = (const float*)d_in[1];
    const float* V = (const float*)d_in[2];
    const int*   M = (const int*)d_in[3];
    float* O = (float*)d_out;
    float* P = O + (size_t)NB * NH * SEQ * DIM;

    u16* Kp = (u16*)d_ws;                                   // 8 MB
    u16* Vp = Kp + (size_t)NHEAD * SEQ * DIM;               // 8 MB (total exactly 16 MB)

    conv_k_kernel<<<dim3(NHEAD * NKT * 64 * 8 / 256), dim3(256), 0, stream>>>(K, Kp);
    conv_v_kernel<<<dim3(NHEAD * NKT), dim3(256), 0, stream>>>(V, Vp);

    sdpa_main_kernel<<<dim3(NHEAD * NQT), dim3(512, 1, 1), 0, stream>>>(Q, Kp, Vp, M, O, P);
}